// Round 16
// baseline (55.914 us; speedup 1.0000x reference)
//
#include <hip/hip_runtime.h>

// Problem constants (B=8, C=128, H=W=48 -> N=2304)
#define NTOK 2304
#define CC   128

typedef __attribute__((ext_vector_type(8))) short bf16x8;
typedef __attribute__((ext_vector_type(4))) float f32x4;

// round-to-nearest-even fp32 -> bf16
__device__ __forceinline__ unsigned f2bf(float f) {
  unsigned u = __builtin_bit_cast(unsigned, f);
  u += 0x7FFFu + ((u >> 16) & 1u);
  return (u >> 16) & 0xFFFFu;
}
__device__ __forceinline__ unsigned pk2(float a, float b) {
  return f2bf(a) | (f2bf(b) << 16);
}

// async global->LDS, 16B per lane (guide §5 / m97; size must be literal 16)
__device__ __forceinline__ void g2l16(const void* g, void* l) {
  __builtin_amdgcn_global_load_lds(
      (const __attribute__((address_space(1))) unsigned int*)g,
      (__attribute__((address_space(3))) unsigned int*)l, 16, 0, 0);
}

// Prep (R13, validated): ONE pass over x,y; exact fp32 norms (sx from x,
// sy from y; reference quirk: P[i][j] = ||x_i||^2 + ||y_j||^2 - 2*y_i.x_j)
// AND bf16 "LDS image": img[b][n] = 256 B row of K-contiguous bf16, slot
// swizzle slot=(k>>3)^(n&15)^((n>>4)&3) pre-applied.
__global__ __launch_bounds__(256) void pwd_prep(
    const float* __restrict__ x, const float* __restrict__ y,
    char* __restrict__ imgX, char* __restrict__ imgY,
    float* __restrict__ sx, float* __restrict__ sy) {
  __shared__ float part[8][32];
  const int tid = threadIdx.x;
  const int nl  = tid & 31;            // token within 32-chunk
  const int cg  = tid >> 5;            // k-group 0..7 (16 k's = 2 octets)
  const int n   = blockIdx.x * 32 + nl;
  const int b   = blockIdx.y;
  const int sel = blockIdx.z;
  const float* src = sel ? y : x;
  char* img = sel ? imgY : imgX;

  const float* p = src + ((size_t)b * CC + cg * 16) * NTOK + n;
  float v[16];
#pragma unroll
  for (int k = 0; k < 16; ++k) v[k] = p[(size_t)k * NTOK];

  float s = 0.f;
#pragma unroll
  for (int k = 0; k < 16; ++k) s = fmaf(v[k], v[k], s);
  part[cg][nl] = s;

  char* row = img + ((size_t)b * NTOK + n) * 256;
  const int swz = (n & 15) ^ ((n >> 4) & 3);
#pragma unroll
  for (int oo = 0; oo < 2; ++oo) {
    const int o = cg * 2 + oo;         // k-octet 0..15
    uint4 wv;
    wv.x = pk2(v[oo * 8 + 0], v[oo * 8 + 1]);
    wv.y = pk2(v[oo * 8 + 2], v[oo * 8 + 3]);
    wv.z = pk2(v[oo * 8 + 4], v[oo * 8 + 5]);
    wv.w = pk2(v[oo * 8 + 6], v[oo * 8 + 7]);
    *(uint4*)(row + ((o ^ swz) * 16)) = wv;
  }
  __syncthreads();
  if (tid < 32) {
    float t = 0.f;
#pragma unroll
    for (int g = 0; g < 8; ++g) t += part[g][tid];
    (sel ? sy : sx)[b * NTOK + blockIdx.x * 32 + tid] = t;
  }
}

// Main GEMM: TWO j-adjacent 64x64 tiles per block (shared y-panel), 32 KB
// LDS -> still 5 blocks/CU. Tile-B x-panel prefetched to REGISTERS at block
// start, written to smX after tile-A's bounce drains. Tile-A stores overlap
// tile-B's panel-write+MFMA+bounce; retire-drain amortized per 32 KB.
//   D[m=j][n=i] = sum_k x[k][j]*y[k][i]  (= y_i . x_j)
__global__ __launch_bounds__(256, 5) void pwd_gemm(
    const char* __restrict__ imgX, const char* __restrict__ imgY,
    const float* __restrict__ sx, const float* __restrict__ sy,
    float* __restrict__ out) {
  __shared__ __attribute__((aligned(16))) char smem[32768];
  char* const smX = smem;            // x panel (tile A, then B): 64 rows * 256 B
  char* const smY = smem + 16384;    // y panel: 64 i-rows * 256 B

  const int tid = threadIdx.x;

  // XCD swizzle (R13, best measured): bid%8 = batch, one batch per XCD L2.
  const int bid = blockIdx.x;
  const int b   = bid & 7;
  const int rem = bid >> 3;            // 0..647
  const int byy = rem / 18;            // 0..35
  const int bxx = rem - byy * 18;      // 0..17
  const int i0 = byy * 64;             // output rows (i)
  const int j0 = bxx * 128;            // tiles at (i0,j0) and (i0,j0+64)

  const int w  = tid >> 6;             // wave 0..3
  const int l  = tid & 63;
  const int lr = l & 15;
  const int lg = l >> 4;
  const int wi = w * 16;               // wave i band

  const char* gx = imgX + ((size_t)b * NTOK + j0) * 256;   // 32 KB (A+B)
  const char* gy = imgY + ((size_t)b * NTOK + i0) * 256;   // 16 KB

  // ---------------- stage: DMA A-panels, reg-prefetch B x-panel -------------
  {
    const int wb = w * 4096;
    const size_t o0 = (size_t)wb + (size_t)l * 16;
#pragma unroll
    for (int it = 0; it < 4; ++it)
      g2l16(gx + o0 + it * 1024, smX + wb + it * 1024);
#pragma unroll
    for (int it = 0; it < 4; ++it)
      g2l16(gy + o0 + it * 1024, smY + wb + it * 1024);
  }
  uint4 breg[4];
#pragma unroll
  for (int it = 0; it < 4; ++it)
    breg[it] = *(const uint4*)(gx + 16384 + tid * 16 + it * 4096);

  // norms (in flight over DMA)
  const float sxr = sx[b * NTOK + i0 + wi + lr];        // x norm at row i
  f32x4 syqA[4];
#pragma unroll
  for (int mf = 0; mf < 4; ++mf)
    syqA[mf] = *(const f32x4*)(sy + b * NTOK + j0 + mf * 16 + lg * 4);

  __syncthreads();   // panels ready (drains DMA + breg loads)

  // ---------------- tile A: MFMA -> bounce -> 256B-run NT stores ------------
  f32x4 acc[4] = {};
#pragma unroll
  for (int ks = 0; ks < 4; ++ks) {
    const int o = ks * 4 + lg;
    bf16x8 ax[4], by;
#pragma unroll
    for (int mf = 0; mf < 4; ++mf) {
      const int n = mf * 16 + lr;
      const int slot = o ^ (n & 15) ^ ((n >> 4) & 3);
      ax[mf] = *(const bf16x8*)(smX + n * 256 + slot * 16);
    }
    {
      const int n = wi + lr;
      const int slot = o ^ (n & 15) ^ ((n >> 4) & 3);
      by = *(const bf16x8*)(smY + n * 256 + slot * 16);
    }
#pragma unroll
    for (int mf = 0; mf < 4; ++mf)
      acc[mf] = __builtin_amdgcn_mfma_f32_16x16x32_bf16(ax[mf], by, acc[mf],
                                                        0, 0, 0);
  }

  float* const tile = (float*)smX;     // bounce reuses the x-panel region
  __syncthreads();                     // all waves done reading smX
#pragma unroll
  for (int mf = 0; mf < 4; ++mf) {
    f32x4 vv;
#pragma unroll
    for (int r = 0; r < 4; ++r)
      vv[r] = sxr + syqA[mf][r] - 2.0f * acc[mf][r];
    const int row = wi + lr;
    const int c16 = mf * 4 + lg;
    *(f32x4*)((char*)tile + row * 256 + ((c16 ^ (row & 15)) * 16)) = vv;
  }
  __syncthreads();                     // bounce visible
#pragma unroll
  for (int it = 0; it < 4; ++it) {
    const int c   = it * 256 + tid;
    const int row = c >> 4;
    const int c16 = c & 15;
    f32x4 vv = *(const f32x4*)((char*)tile + row * 256 +
                               ((c16 ^ (row & 15)) * 16));
    __builtin_nontemporal_store(
        vv, (f32x4*)(out + ((size_t)b * NTOK + i0 + row) * NTOK + j0 + c16 * 4));
  }

  // tile-B norms (L2-hot; latency hides under B panel write + MFMA)
  f32x4 syqB[4];
#pragma unroll
  for (int mf = 0; mf < 4; ++mf)
    syqB[mf] = *(const f32x4*)(sy + b * NTOK + j0 + 64 + mf * 16 + lg * 4);

  __syncthreads();                     // bounce reads done -> smX reusable

  // ---------------- write B x-panel from registers (linear, conflict-free) --
#pragma unroll
  for (int it = 0; it < 4; ++it)
    *(uint4*)(smX + tid * 16 + it * 4096) = breg[it];
  __syncthreads();                     // B panel ready

  // ---------------- tile B: MFMA -> bounce -> stores ------------------------
  f32x4 acc2[4] = {};
#pragma unroll
  for (int ks = 0; ks < 4; ++ks) {
    const int o = ks * 4 + lg;
    bf16x8 ax[4], by;
#pragma unroll
    for (int mf = 0; mf < 4; ++mf) {
      const int n = mf * 16 + lr;
      const int slot = o ^ (n & 15) ^ ((n >> 4) & 3);
      ax[mf] = *(const bf16x8*)(smX + n * 256 + slot * 16);
    }
    {
      const int n = wi + lr;
      const int slot = o ^ (n & 15) ^ ((n >> 4) & 3);
      by = *(const bf16x8*)(smY + n * 256 + slot * 16);
    }
#pragma unroll
    for (int mf = 0; mf < 4; ++mf)
      acc2[mf] = __builtin_amdgcn_mfma_f32_16x16x32_bf16(ax[mf], by, acc2[mf],
                                                         0, 0, 0);
  }

  __syncthreads();                     // all waves done reading smX
#pragma unroll
  for (int mf = 0; mf < 4; ++mf) {
    f32x4 vv;
#pragma unroll
    for (int r = 0; r < 4; ++r)
      vv[r] = sxr + syqB[mf][r] - 2.0f * acc2[mf][r];
    const int row = wi + lr;
    const int c16 = mf * 4 + lg;
    *(f32x4*)((char*)tile + row * 256 + ((c16 ^ (row & 15)) * 16)) = vv;
  }
  __syncthreads();                     // bounce visible
#pragma unroll
  for (int it = 0; it < 4; ++it) {
    const int c   = it * 256 + tid;
    const int row = c >> 4;
    const int c16 = c & 15;
    f32x4 vv = *(const f32x4*)((char*)tile + row * 256 +
                               ((c16 ^ (row & 15)) * 16));
    __builtin_nontemporal_store(
        vv, (f32x4*)(out + ((size_t)b * NTOK + i0 + row) * NTOK + j0 + 64 + c16 * 4));
  }
}

extern "C" void kernel_launch(void* const* d_in, const int* in_sizes, int n_in,
                              void* d_out, int out_size, void* d_ws, size_t ws_size,
                              hipStream_t stream) {
  (void)in_sizes; (void)n_in; (void)out_size; (void)ws_size;
  const float* x = (const float*)d_in[0];
  const float* y = (const float*)d_in[1];
  float* out = (float*)d_out;

  // workspace layout: bf16 images (2 x 4.72 MB) + norms (2 x 73.7 KB)
  char* imgX = (char*)d_ws;
  char* imgY = imgX + (size_t)8 * NTOK * 256;
  float* sx  = (float*)(imgY + (size_t)8 * NTOK * 256);
  float* sy  = sx + 8 * NTOK;

  dim3 gp(NTOK / 32, 8, 2);              // 1152 blocks
  pwd_prep<<<gp, dim3(256), 0, stream>>>(x, y, imgX, imgY, sx, sy);

  dim3 gg(36 * 18 * 8);                  // two 64x64 tiles per block
  pwd_gemm<<<gg, dim3(256), 0, stream>>>(imgX, imgY, sx, sy, out);
}

// Round 17
// 48.568 us; speedup vs baseline: 1.1513x; 1.1513x over previous
//
#include <hip/hip_runtime.h>

// Problem constants (B=8, C=128, H=W=48 -> N=2304)
#define NTOK 2304
#define CC   128
#define IMB  ((size_t)NTOK * 256)     // image bytes per batch

typedef __attribute__((ext_vector_type(8))) short bf16x8;
typedef __attribute__((ext_vector_type(4))) float f32x4;

// round-to-nearest-even fp32 -> bf16
__device__ __forceinline__ unsigned f2bf(float f) {
  unsigned u = __builtin_bit_cast(unsigned, f);
  u += 0x7FFFu + ((u >> 16) & 1u);
  return (u >> 16) & 0xFFFFu;
}
__device__ __forceinline__ unsigned pk2(float a, float b) {
  return f2bf(a) | (f2bf(b) << 16);
}

// Prep: ONE pass over x,y; exact fp32 norms (sx from x, sy from y; reference
// quirk: P[i][j] = ||x_i||^2 + ||y_j||^2 - 2*y_i.x_j) AND a bf16 image in
// FRAGMENT-MAJOR layout: chunk(n, o) at
//   (n>>4)*4096 + (o>>2)*1024 + (o&3)*256 + (n&15)*16
// (n = token, o = k-octet 0..15). With this layout the gemm's fragment load
// for (16-token group, MFMA #ks) is base + ks*1024 + lane*16 -- a perfectly
// coalesced 1 KB wave load, no LDS staging needed.
__global__ __launch_bounds__(256) void pwd_prep(
    const float* __restrict__ x, const float* __restrict__ y,
    char* __restrict__ imgX, char* __restrict__ imgY,
    float* __restrict__ sx, float* __restrict__ sy) {
  __shared__ float part[8][32];
  const int tid = threadIdx.x;
  const int nl  = tid & 31;            // token within 32-chunk
  const int cg  = tid >> 5;            // k-group 0..7 (16 k's = 2 octets)
  const int n   = blockIdx.x * 32 + nl;
  const int b   = blockIdx.y;
  const int sel = blockIdx.z;
  const float* src = sel ? y : x;
  char* img = (sel ? imgY : imgX) + (size_t)b * IMB;

  const float* p = src + ((size_t)b * CC + cg * 16) * NTOK + n;
  float v[16];
#pragma unroll
  for (int k = 0; k < 16; ++k) v[k] = p[(size_t)k * NTOK];

  float s = 0.f;
#pragma unroll
  for (int k = 0; k < 16; ++k) s = fmaf(v[k], v[k], s);
  part[cg][nl] = s;

  const int rbase = (n >> 4) * 4096 + (n & 15) * 16;
#pragma unroll
  for (int oo = 0; oo < 2; ++oo) {
    const int o = cg * 2 + oo;         // k-octet 0..15
    uint4 wv;
    wv.x = pk2(v[oo * 8 + 0], v[oo * 8 + 1]);
    wv.y = pk2(v[oo * 8 + 2], v[oo * 8 + 3]);
    wv.z = pk2(v[oo * 8 + 4], v[oo * 8 + 5]);
    wv.w = pk2(v[oo * 8 + 6], v[oo * 8 + 7]);
    *(uint4*)(img + rbase + (o >> 2) * 1024 + (o & 3) * 256) = wv;
  }
  __syncthreads();
  if (tid < 32) {
    float t = 0.f;
#pragma unroll
    for (int g = 0; g < 8; ++g) t += part[g][tid];
    (sel ? sy : sx)[b * NTOK + blockIdx.x * 32 + tid] = t;
  }
}

// Main GEMM: fully BARRIER-FREE, wave-independent 64x64 tiles.
//   D[m=j][n=i] = sum_k x[k][j]*y[k][i]  (= y_i . x_j)
// Each wave: 16+16 coalesced 1KB fragment loads L2->VGPR (fragment-major
// image), 64 MFMAs into acc[4][4], then per-16-row chunk: bounce through a
// PRIVATE 4KB LDS slice (in-order per-wave DS, no __syncthreads) and store
// 4-row x 256B runs (NT). 4 waves/block, 16KB LDS, <=128 VGPR -> 16
// independent waves/CU; no phase-locking possible.
__global__ __launch_bounds__(256, 4) void pwd_gemm(
    const char* __restrict__ imgX, const char* __restrict__ imgY,
    const float* __restrict__ sx, const float* __restrict__ sy,
    float* __restrict__ out) {
  __shared__ __attribute__((aligned(16))) char smem[16384];

  const int tid = threadIdx.x;
  const int w  = tid >> 6;             // wave 0..3
  const int l  = tid & 63;
  const int lr = l & 15;
  const int lg = l >> 4;

  // XCD mapping (R13, best measured): bid%8 = batch -> one batch per XCD L2.
  const int bid = blockIdx.x;
  const int b   = bid & 7;
  const int rem = bid >> 3;            // 0..323
  const int byy = rem / 9;             // 0..35
  const int bxq = rem - byy * 9;       // 0..8
  const int i0 = byy * 64;             // tile rows (i)
  const int j0 = bxq * 256 + w * 64;   // tile cols (j), one per wave

  const char* gA = imgX + (size_t)b * IMB + (j0 >> 4) * 4096;  // x, j side
  const char* gB = imgY + (size_t)b * IMB + (i0 >> 4) * 4096;  // y, i side

  // ---------------- compute: 64 MFMAs, fragments straight from L2 -----------
  f32x4 acc[4][4] = {};
#pragma unroll
  for (int ks = 0; ks < 4; ++ks) {
    bf16x8 a[4], bv[4];
#pragma unroll
    for (int mf = 0; mf < 4; ++mf)
      a[mf] = *(const bf16x8*)(gA + mf * 4096 + ks * 1024 + l * 16);
#pragma unroll
    for (int nf = 0; nf < 4; ++nf)
      bv[nf] = *(const bf16x8*)(gB + nf * 4096 + ks * 1024 + l * 16);
#pragma unroll
    for (int mf = 0; mf < 4; ++mf)
#pragma unroll
      for (int nf = 0; nf < 4; ++nf)
        acc[mf][nf] = __builtin_amdgcn_mfma_f32_16x16x32_bf16(
            a[mf], bv[nf], acc[mf][nf], 0, 0, 0);
  }

  // ---------------- norms (loaded after MFMA to cap register pressure) ------
  float sxr[4];
#pragma unroll
  for (int nf = 0; nf < 4; ++nf)                 // x norm at row i
    sxr[nf] = sx[b * NTOK + i0 + nf * 16 + lr];
  f32x4 syq[4];
#pragma unroll
  for (int mf = 0; mf < 4; ++mf)                 // y norms at j quad
    syq[mf] = *(const f32x4*)(sy + b * NTOK + j0 + mf * 16 + lg * 4);

  // ---------------- epilogue: per-wave private bounce, no barriers ----------
  // chunk nf (16 rows x 64 cols = 4 KB): write swizzled (c16 ^ row&15),
  // read back as 4-row x 256 B runs, NT store. All DS ops within one wave
  // (in-order LDS pipe) -> no __syncthreads.
  char* const myb = smem + w * 4096;
#pragma unroll
  for (int nf = 0; nf < 4; ++nf) {
#pragma unroll
    for (int mf = 0; mf < 4; ++mf) {
      f32x4 vv;
#pragma unroll
      for (int r = 0; r < 4; ++r)
        vv[r] = sxr[nf] + syq[mf][r] - 2.0f * acc[mf][nf][r];
      const int c16 = mf * 4 + lg;
      *(f32x4*)(myb + lr * 256 + ((c16 ^ lr) * 16)) = vv;
    }
#pragma unroll
    for (int it = 0; it < 4; ++it) {
      const int row = it * 4 + lg;
      f32x4 vv = *(const f32x4*)(myb + row * 256 + ((lr ^ row) * 16));
      __builtin_nontemporal_store(
          vv, (f32x4*)(out + ((size_t)b * NTOK + i0 + nf * 16 + row) * NTOK +
                       j0 + lr * 4));
    }
  }
}

extern "C" void kernel_launch(void* const* d_in, const int* in_sizes, int n_in,
                              void* d_out, int out_size, void* d_ws, size_t ws_size,
                              hipStream_t stream) {
  (void)in_sizes; (void)n_in; (void)out_size; (void)ws_size;
  const float* x = (const float*)d_in[0];
  const float* y = (const float*)d_in[1];
  float* out = (float*)d_out;

  // workspace layout: bf16 images (2 x 4.72 MB) + norms (2 x 73.7 KB)
  char* imgX = (char*)d_ws;
  char* imgY = imgX + 8 * IMB;
  float* sx  = (float*)(imgY + 8 * IMB);
  float* sy  = sx + 8 * NTOK;

  dim3 gp(NTOK / 32, 8, 2);              // 1152 blocks
  pwd_prep<<<gp, dim3(256), 0, stream>>>(x, y, imgX, imgY, sx, sy);

  dim3 gg(36 * 9 * 8);                   // 2592 blocks x 4 indep. wave-tiles
  pwd_gemm<<<gg, dim3(256), 0, stream>>>(imgX, imgY, sx, sy, out);
}

// Round 18
// 42.553 us; speedup vs baseline: 1.3140x; 1.1414x over previous
//
#include <hip/hip_runtime.h>

// Problem constants (B=8, C=128, H=W=48 -> N=2304)
#define NTOK 2304
#define CC   128

typedef __attribute__((ext_vector_type(8))) short bf16x8;
typedef __attribute__((ext_vector_type(4))) float f32x4;

// round-to-nearest-even fp32 -> bf16
__device__ __forceinline__ unsigned f2bf(float f) {
  unsigned u = __builtin_bit_cast(unsigned, f);
  u += 0x7FFFu + ((u >> 16) & 1u);
  return (u >> 16) & 0xFFFFu;
}
__device__ __forceinline__ unsigned pk2(float a, float b) {
  return f2bf(a) | (f2bf(b) << 16);
}

// async global->LDS, 16B per lane; LDS dest = wave-uniform base + lane*16,
// global src per-lane (guide §5 / m97; size must be literal 16)
__device__ __forceinline__ void g2l16(const void* g, void* l) {
  __builtin_amdgcn_global_load_lds(
      (const __attribute__((address_space(1))) unsigned int*)g,
      (__attribute__((address_space(3))) unsigned int*)l, 16, 0, 0);
}

// Prep (best measured, R13): ONE pass over x,y; exact fp32 norms (sx from x,
// sy from y; reference quirk: P[i][j] = ||x_i||^2 + ||y_j||^2 - 2*y_i.x_j)
// AND bf16 "LDS image": img[b][n] = 256 B row of K-contiguous bf16, slot
// swizzle slot=(k>>3)^(n&15)^((n>>4)&3) pre-applied.
__global__ __launch_bounds__(256) void pwd_prep(
    const float* __restrict__ x, const float* __restrict__ y,
    char* __restrict__ imgX, char* __restrict__ imgY,
    float* __restrict__ sx, float* __restrict__ sy) {
  __shared__ float part[8][32];
  const int tid = threadIdx.x;
  const int nl  = tid & 31;            // token within 32-chunk
  const int cg  = tid >> 5;            // k-group 0..7 (16 k's = 2 octets)
  const int n   = blockIdx.x * 32 + nl;
  const int b   = blockIdx.y;
  const int sel = blockIdx.z;
  const float* src = sel ? y : x;
  char* img = sel ? imgY : imgX;

  const float* p = src + ((size_t)b * CC + cg * 16) * NTOK + n;
  float v[16];
#pragma unroll
  for (int k = 0; k < 16; ++k) v[k] = p[(size_t)k * NTOK];

  float s = 0.f;
#pragma unroll
  for (int k = 0; k < 16; ++k) s = fmaf(v[k], v[k], s);
  part[cg][nl] = s;

  char* row = img + ((size_t)b * NTOK + n) * 256;
  const int swz = (n & 15) ^ ((n >> 4) & 3);
#pragma unroll
  for (int oo = 0; oo < 2; ++oo) {
    const int o = cg * 2 + oo;         // k-octet 0..15
    uint4 wv;
    wv.x = pk2(v[oo * 8 + 0], v[oo * 8 + 1]);
    wv.y = pk2(v[oo * 8 + 2], v[oo * 8 + 3]);
    wv.z = pk2(v[oo * 8 + 4], v[oo * 8 + 5]);
    wv.w = pk2(v[oo * 8 + 6], v[oo * 8 + 7]);
    *(uint4*)(row + ((o ^ swz) * 16)) = wv;
  }
  __syncthreads();
  if (tid < 32) {
    float t = 0.f;
#pragma unroll
    for (int g = 0; g < 8; ++g) t += part[g][tid];
    (sel ? sy : sx)[b * NTOK + blockIdx.x * 32 + tid] = t;
  }
}

// Main GEMM (R13, best measured = 42.9 us): 64x64 tile, 256 thr / 4 waves,
// LDS 32KB -> 5 blocks/CU (20 waves/CU, decorrelated block phases).
// Staging = 8x global_load_lds dwordx4/thread from pre-swizzled bf16 image.
// Epilogue: LDS bounce (swizzled, conflict-free) -> 4-row x 256B-run NT
// stores. Batch-per-XCD block mapping for L2-resident image panels.
//   D[m=j][n=i] = sum_k x[k][j]*y[k][i]  (= y_i . x_j)
__global__ __launch_bounds__(256, 5) void pwd_gemm(
    const char* __restrict__ imgX, const char* __restrict__ imgY,
    const float* __restrict__ sx, const float* __restrict__ sy,
    float* __restrict__ out) {
  __shared__ __attribute__((aligned(16))) char smem[32768];
  char* const smX = smem;            // x panel: 64 j-rows * 256 B
  char* const smY = smem + 16384;    // y panel: 64 i-rows * 256 B

  const int tid = threadIdx.x;

  // XCD swizzle: grid 10368 = 8*1296; bid%8 = batch (one batch per XCD L2).
  const int bid = blockIdx.x;
  const int b   = bid & 7;
  const int rem = bid >> 3;            // 0..1295
  const int byy = rem / 36;
  const int bxx = rem - byy * 36;
  const int i0 = byy * 64;             // output rows (i)
  const int j0 = bxx * 64;             // output cols (j)

  const int w  = tid >> 6;             // wave 0..3
  const int l  = tid & 63;
  const int lr = l & 15;
  const int lg = l >> 4;
  const int wi = w * 16;               // wave i band

  // ---------------- stage panels via async DMA ------------------------------
  // wave w copies 4KB chunk w of each 16KB panel (4 x 1KB instructions).
  {
    const char* gx = imgX + ((size_t)b * NTOK + j0) * 256;
    const char* gy = imgY + ((size_t)b * NTOK + i0) * 256;
    const int wb = w * 4096;
    const size_t o0 = (size_t)wb + (size_t)l * 16;
#pragma unroll
    for (int it = 0; it < 4; ++it)
      g2l16(gx + o0 + it * 1024, smX + wb + it * 1024);
#pragma unroll
    for (int it = 0; it < 4; ++it)
      g2l16(gy + o0 + it * 1024, smY + wb + it * 1024);
  }

  // ---------------- hoist norms into registers (in flight over DMA) ---------
  const float sxr = sx[b * NTOK + i0 + wi + lr];        // x norm at row i
  f32x4 syq[4];
#pragma unroll
  for (int mf = 0; mf < 4; ++mf)                         // y norms at j quad
    syq[mf] = *(const f32x4*)(sy + b * NTOK + j0 + mf * 16 + lg * 4);

  __syncthreads();   // drains vmcnt (DMA complete)

  // ---------------- compute: wave tile 64j x 16i ----------------------------
  f32x4 acc[4] = {};
#pragma unroll
  for (int ks = 0; ks < 4; ++ks) {
    const int o = ks * 4 + lg;           // 16B slot (8 k's)
    bf16x8 ax[4], by;
#pragma unroll
    for (int mf = 0; mf < 4; ++mf) {     // A-frag rows = j
      const int n = mf * 16 + lr;
      const int slot = o ^ (n & 15) ^ ((n >> 4) & 3);
      ax[mf] = *(const bf16x8*)(smX + n * 256 + slot * 16);
    }
    {                                    // B-frag rows = i
      const int n = wi + lr;
      const int slot = o ^ (n & 15) ^ ((n >> 4) & 3);
      by = *(const bf16x8*)(smY + n * 256 + slot * 16);
    }
#pragma unroll
    for (int mf = 0; mf < 4; ++mf)
      acc[mf] = __builtin_amdgcn_mfma_f32_16x16x32_bf16(ax[mf], by, acc[mf],
                                                        0, 0, 0);
  }

  // ---------------- epilogue: LDS bounce -> 256B-run NT stores --------------
  // tile[64][64] fp32 (16 KB), 16B chunks XOR-swizzled: chunk addr =
  // row*256 + ((c16 ^ (row&15))*16). Both bounce write and read are <=2-way
  // bank aliased (free).
  {
    float* const tile = (float*)smem;    // panels dead after compute
    __syncthreads();
#pragma unroll
    for (int mf = 0; mf < 4; ++mf) {
      f32x4 vv;
#pragma unroll
      for (int r = 0; r < 4; ++r)
        vv[r] = sxr + syq[mf][r] - 2.0f * acc[mf][r];
      const int row = wi + lr;           // local i
      const int c16 = mf * 4 + lg;       // 16B chunk within row (local j/4)
      *(f32x4*)((char*)tile + row * 256 + ((c16 ^ (row & 15)) * 16)) = vv;
    }
    __syncthreads();
    // stream out: instr = 64 consecutive 16B chunks = 4 rows x 256 B contig
#pragma unroll
    for (int it = 0; it < 4; ++it) {
      const int c   = it * 256 + tid;    // chunk id 0..1023
      const int row = c >> 4;
      const int c16 = c & 15;
      f32x4 vv = *(const f32x4*)((char*)tile + row * 256 +
                                 ((c16 ^ (row & 15)) * 16));
      __builtin_nontemporal_store(
          vv, (f32x4*)(out + ((size_t)b * NTOK + i0 + row) * NTOK + j0 + c16 * 4));
    }
  }
}

extern "C" void kernel_launch(void* const* d_in, const int* in_sizes, int n_in,
                              void* d_out, int out_size, void* d_ws, size_t ws_size,
                              hipStream_t stream) {
  (void)in_sizes; (void)n_in; (void)out_size; (void)ws_size;
  const float* x = (const float*)d_in[0];
  const float* y = (const float*)d_in[1];
  float* out = (float*)d_out;

  // workspace layout: bf16 images (2 x 4.72 MB) + norms (2 x 73.7 KB)
  char* imgX = (char*)d_ws;
  char* imgY = imgX + (size_t)8 * NTOK * 256;
  float* sx  = (float*)(imgY + (size_t)8 * NTOK * 256);
  float* sy  = sx + 8 * NTOK;

  dim3 gp(NTOK / 32, 8, 2);              // 1152 blocks
  pwd_prep<<<gp, dim3(256), 0, stream>>>(x, y, imgX, imgY, sx, sy);

  dim3 gg(36 * 36 * 8);                  // one 64x64 tile per block
  pwd_gemm<<<gg, dim3(256), 0, stream>>>(imgX, imgY, sx, sy, out);
}